// Round 1
// baseline (306.049 us; speedup 1.0000x reference)
//
#include <hip/hip_runtime.h>
#include <hip/hip_bf16.h>

// CRF forward: B=512 chains, T=1024, L=48.
// Scaled-probability-domain scan: e'[m] = (sum_l e[l]*Et[l][m]) * w[m],
// Et = exp(trans) in 48 VGPRs per lane (lane = destination label m),
// e broadcast via v_readlane (no LDS round trip on the critical path),
// w = 2^(y_pred*log2e - c) with lagged normalizer c = log2(e_prev[0]).
// point/trans scores fused in (labels from one-hot via ballot+ffs).

constexpr int Bb = 512;
constexpr int Tt = 1024;
constexpr int Ll = 48;
constexpr int PF = 4;   // prefetch depth (steps)

#define LOG2E_F 1.44269504088896340736f
#define LN2_F   0.69314718055994530942f

__device__ __forceinline__ float rl_f(float v, int l) {
    return __uint_as_float(__builtin_amdgcn_readlane(__float_as_uint(v), (unsigned)l));
}

__device__ __forceinline__ float fexp2(float x) {
#if __has_builtin(__builtin_amdgcn_exp2f)
    return __builtin_amdgcn_exp2f(x);
#else
    return exp2f(x);
#endif
}

__device__ __forceinline__ float flog2(float x) {
#if __has_builtin(__builtin_amdgcn_logf)
    return __builtin_amdgcn_logf(x);   // v_log_f32 = log2
#else
    return __log2f(x);
#endif
}

__global__ __launch_bounds__(64, 1)
void crf_fwd_kernel(const float* __restrict__ y_true,
                    const float* __restrict__ y_pred,
                    const float* __restrict__ trans,
                    float* __restrict__ out)
{
    const int b    = blockIdx.x;
    const int lane = threadIdx.x;
    const int ml   = lane < Ll ? lane : (Ll - 1);   // clamped label index
    const bool act = lane < Ll;

    // trans table in LDS (for trans_score gather) + Et column in registers
    __shared__ float str[Ll * Ll];
    for (int i = threadIdx.x; i < Ll * Ll; i += 64) str[i] = trans[i];
    __syncthreads();

    float Et[Ll];
    #pragma unroll
    for (int l = 0; l < Ll; ++l)
        Et[l] = fexp2(str[l * Ll + ml] * LOG2E_F);   // exp(trans[l][m])

    const float* __restrict__ yprow = y_pred + (size_t)b * Tt * Ll;
    const float* __restrict__ ytrow = y_true + (size_t)b * Tt * Ll;

    // t = 0 init
    float raw0 = yprow[ml];
    float e  = fexp2(raw0 * LOG2E_F);   // e_0[m] = 2^(alpha0[m]*log2e), S=0
    float S  = 0.f;                     // accumulated log2 normalizers
    float ts = 0.f;

    unsigned long long m0 = __ballot(act && (ytrow[ml] > 0.5f));
    int labPrev = __ffsll(m0) - 1;
    float ps = rl_f(raw0, labPrev);     // point score, t=0 term

    // one scan step (captures all state by reference)
    auto step = [&](float raw, float ytv) {
        // --- w path (off critical path: depends only on prev e[0] + data)
        float e0 = rl_f(e, 0);
        float c  = flog2(e0);
        S += c;
        float w = fexp2(fmaf(raw, LOG2E_F, -c));   // 2^(emit*log2e - c)

        // --- score path (off critical path)
        unsigned long long bm = __ballot(act && (ytv > 0.5f));
        int lab = __ffsll(bm) - 1;
        ps += rl_f(raw, lab);                       // y_pred[b,t,lab]
        ts += str[labPrev * Ll + lab];              // trans[labPrev,lab]
        labPrev = lab;

        // --- critical path: 48 readlane-broadcast fmacs, 4 accumulators
        float a0 = 0.f, a1 = 0.f, a2 = 0.f, a3 = 0.f;
        #pragma unroll
        for (int l = 0; l < Ll; l += 4) {
            a0 = fmaf(rl_f(e, l + 0), Et[l + 0], a0);
            a1 = fmaf(rl_f(e, l + 1), Et[l + 1], a1);
            a2 = fmaf(rl_f(e, l + 2), Et[l + 2], a2);
            a3 = fmaf(rl_f(e, l + 3), Et[l + 3], a3);
        }
        e = ((a0 + a1) + (a2 + a3)) * w;
    };

    // prefetch pipeline: pfP/pfT hold rows t0..t0+3
    float pfP[PF], pfT[PF];
    #pragma unroll
    for (int j = 0; j < PF; ++j) {
        pfP[j] = yprow[(1 + j) * Ll + ml];
        pfT[j] = ytrow[(1 + j) * Ll + ml];
    }

    // main: 255 chunks of 4 -> steps t = 1..1020
    for (int t0 = 1; t0 <= Tt - PF - 3; t0 += PF) {
        #pragma unroll
        for (int j = 0; j < PF; ++j) {
            float raw = pfP[j];
            float ytv = pfT[j];
            int tn = t0 + j + PF;
            tn = tn < Tt ? tn : (Tt - 1);           // clamp (harmless reload)
            pfP[j] = yprow[tn * Ll + ml];
            pfT[j] = ytrow[tn * Ll + ml];
            step(raw, ytv);
        }
    }
    // tail: t = 1021, 1022, 1023
    step(pfP[0], pfT[0]);
    step(pfP[1], pfT[1]);
    step(pfP[2], pfT[2]);

    // epilogue: log_norm = ln2 * (S + log2(sum_m e[m]))
    float es = act ? e : 0.f;
    #pragma unroll
    for (int off = 32; off >= 1; off >>= 1) es += __shfl_xor(es, off);

    if (lane == 0) {
        float log_norm = LN2_F * (S + flog2(es));
        out[b] = log_norm - ps - ts;
    }
}

extern "C" void kernel_launch(void* const* d_in, const int* in_sizes, int n_in,
                              void* d_out, int out_size, void* d_ws, size_t ws_size,
                              hipStream_t stream) {
    const float* y_true = (const float*)d_in[0];
    const float* y_pred = (const float*)d_in[1];
    const float* trans  = (const float*)d_in[2];
    float* out = (float*)d_out;

    crf_fwd_kernel<<<Bb, 64, 0, stream>>>(y_true, y_pred, trans, out);
}

// Round 2
// 253.151 us; speedup vs baseline: 1.2090x; 1.2090x over previous
//
#include <hip/hip_runtime.h>
#include <hip/hip_bf16.h>

// CRF forward: B=512 chains, T=1024, L=48. One wave per chain.
// Scaled-probability scan: e'[m] = (sum_l e[l]*Et[l][m]) * w[m].
// Broadcast of e via LDS: 1 ds_write + 12 uniform ds_read_b128 (HW broadcast),
// fmacs are pure-VGPR (no readlane/SGPR hazards). Et held in 12 named float4s
// (static accesses only -> guaranteed register-resident).
// w = 2^(emit*log2e - c), lagged normalizer c = log2(e_prev[0]) via 1 ds_read.

constexpr int Bb = 512;
constexpr int Tt = 1024;
constexpr int Ll = 48;
constexpr int PF = 4;   // prefetch depth (steps)

#define LOG2E_F 1.44269504088896340736f
#define LN2_F   0.69314718055994530942f

__device__ __forceinline__ float rl_f(float v, int l) {
    return __uint_as_float(__builtin_amdgcn_readlane(__float_as_uint(v), (unsigned)l));
}
__device__ __forceinline__ float fexp2(float x) {
    return __builtin_amdgcn_exp2f(x);
}
__device__ __forceinline__ float flog2(float x) {
    return __builtin_amdgcn_logf(x);   // v_log_f32 = log2
}

__global__ __launch_bounds__(64, 1)
void crf_fwd_kernel(const float* __restrict__ y_true,
                    const float* __restrict__ y_pred,
                    const float* __restrict__ trans,
                    float* __restrict__ out)
{
    const int b    = blockIdx.x;
    const int lane = threadIdx.x;
    const int ml   = lane < Ll ? lane : (Ll - 1);   // clamped dest-label index
    const bool act = lane < Ll;

    __shared__ float str[Ll * Ll];                  // trans (for score gather + Et build)
    __shared__ __align__(16) float ebuf[64];        // e broadcast buffer
    for (int i = lane; i < Ll * Ll; i += 64) str[i] = trans[i];
    __syncthreads();

    // Et[l] = exp(trans[l][ml]) in 12 NAMED float4s — static accesses only.
#define MK_E(j) const float4 E##j = make_float4(                      \
        fexp2(str[(4*(j)+0)*Ll + ml] * LOG2E_F),                      \
        fexp2(str[(4*(j)+1)*Ll + ml] * LOG2E_F),                      \
        fexp2(str[(4*(j)+2)*Ll + ml] * LOG2E_F),                      \
        fexp2(str[(4*(j)+3)*Ll + ml] * LOG2E_F));
    MK_E(0) MK_E(1) MK_E(2)  MK_E(3)
    MK_E(4) MK_E(5) MK_E(6)  MK_E(7)
    MK_E(8) MK_E(9) MK_E(10) MK_E(11)
#undef MK_E

    const float* __restrict__ yprow = y_pred + (size_t)b * Tt * Ll;
    const float* __restrict__ ytrow = y_true + (size_t)b * Tt * Ll;

    // t = 0 init
    float raw0 = yprow[ml];
    float e = fexp2(raw0 * LOG2E_F);    // e_0[m] = 2^(alpha0[m]*log2e), S=0
    float S = 0.f;                      // accumulated log2 normalizers
    float ts = 0.f;

    unsigned long long m0 = __ballot(act && (ytrow[ml] > 0.5f));
    int labPrev = __ffsll(m0) - 1;
    float ps = rl_f(raw0, labPrev);     // point score, t=0 term

    auto step = [&](float raw, float ytv) {
        // publish current e to LDS (DS pipe is in-order within the wave;
        // the read below aliases -> compiler keeps program order)
        ebuf[lane] = e;

        // normalizer path (off fmac critical path): c = log2(e[0])
        float e0 = ebuf[0];
        float c  = flog2(e0);
        S += c;
        float w = fexp2(fmaf(raw, LOG2E_F, -c));   // 2^(emit*log2e - c)

        // score path (off critical path)
        unsigned long long bm = __ballot(act && (ytv > 0.5f));
        int lab = __ffsll(bm) - 1;
        ps += rl_f(raw, lab);                       // y_pred[b,t,lab]
        ts += str[labPrev * Ll + lab];              // trans[labPrev,lab]
        labPrev = lab;

        // matvec: 12 uniform-address b128 broadcasts + 48 pure-VGPR fmacs
        float a0 = 0.f, a1 = 0.f, a2 = 0.f, a3 = 0.f;
#define ACC4(j) { float4 bc = *(const float4*)&ebuf[4*(j)];           \
        a0 = fmaf(bc.x, E##j.x, a0); a1 = fmaf(bc.y, E##j.y, a1);     \
        a2 = fmaf(bc.z, E##j.z, a2); a3 = fmaf(bc.w, E##j.w, a3); }
        ACC4(0) ACC4(1) ACC4(2)  ACC4(3)
        ACC4(4) ACC4(5) ACC4(6)  ACC4(7)
        ACC4(8) ACC4(9) ACC4(10) ACC4(11)
#undef ACC4
        e = ((a0 + a1) + (a2 + a3)) * w;
    };

    // prefetch pipeline: pfP/pfT hold rows t0..t0+PF-1
    float pfP[PF], pfT[PF];
    #pragma unroll
    for (int j = 0; j < PF; ++j) {
        pfP[j] = yprow[(1 + j) * Ll + ml];
        pfT[j] = ytrow[(1 + j) * Ll + ml];
    }

    // main: steps t = 1..1020 in chunks of PF
    for (int t0 = 1; t0 <= Tt - PF - 3; t0 += PF) {
        #pragma unroll
        for (int j = 0; j < PF; ++j) {
            float raw = pfP[j];
            float ytv = pfT[j];
            int tn = t0 + j + PF;
            tn = tn < Tt ? tn : (Tt - 1);           // clamp (harmless reload)
            pfP[j] = yprow[tn * Ll + ml];
            pfT[j] = ytrow[tn * Ll + ml];
            step(raw, ytv);
        }
    }
    // tail: t = 1021, 1022, 1023
    step(pfP[0], pfT[0]);
    step(pfP[1], pfT[1]);
    step(pfP[2], pfT[2]);

    // epilogue: log_norm = ln2 * (S + log2(sum_m e[m]))
    float es = act ? e : 0.f;
    #pragma unroll
    for (int off = 32; off >= 1; off >>= 1) es += __shfl_xor(es, off);

    if (lane == 0) {
        float log_norm = LN2_F * (S + flog2(es));
        out[b] = log_norm - ps - ts;
    }
}

extern "C" void kernel_launch(void* const* d_in, const int* in_sizes, int n_in,
                              void* d_out, int out_size, void* d_ws, size_t ws_size,
                              hipStream_t stream) {
    const float* y_true = (const float*)d_in[0];
    const float* y_pred = (const float*)d_in[1];
    const float* trans  = (const float*)d_in[2];
    float* out = (float*)d_out;

    crf_fwd_kernel<<<Bb, 64, 0, stream>>>(y_true, y_pred, trans, out);
}

// Round 3
// 253.131 us; speedup vs baseline: 1.2091x; 1.0001x over previous
//
#include <hip/hip_runtime.h>
#include <hip/hip_bf16.h>

// CRF forward: B=512 chains, T=1024, L=48. One wave per chain.
// Scaled-probability scan: e'[m] = (sum_l e[l]*Et[l][m]) * w[m].
// e broadcast via LDS: 1 ds_write + 12 uniform ds_read_b128 (HW broadcast).
// Et = exp(trans[l][m]) held in 48 NAMED float scalars (static accesses only,
// no lambda/capture frame -> guaranteed VGPR-resident).
// w = 2^(emit*log2e - c), lagged normalizer c = log2(e_prev[0]).

constexpr int Bb = 512;
constexpr int Tt = 1024;
constexpr int Ll = 48;
constexpr int PF = 4;   // prefetch depth (steps)

#define LOG2E_F 1.44269504088896340736f
#define LN2_F   0.69314718055994530942f

__device__ __forceinline__ float rl_f(float v, int l) {
    return __uint_as_float(__builtin_amdgcn_readlane(__float_as_uint(v), (unsigned)l));
}
__device__ __forceinline__ float fexp2(float x) {
    return __builtin_amdgcn_exp2f(x);
}
__device__ __forceinline__ float flog2(float x) {
    return __builtin_amdgcn_logf(x);   // v_log_f32 = log2
}

__global__ __launch_bounds__(64, 1)
void crf_fwd_kernel(const float* __restrict__ y_true,
                    const float* __restrict__ y_pred,
                    const float* __restrict__ trans,
                    float* __restrict__ out)
{
    const int b    = blockIdx.x;
    const int lane = threadIdx.x;
    const int ml   = lane < Ll ? lane : (Ll - 1);   // clamped dest-label index
    const bool act = lane < Ll;

    __shared__ float str[Ll * Ll];                  // trans (score gather + Et build)
    __shared__ __align__(16) float ebuf[64];        // e broadcast buffer
    for (int i = lane; i < Ll * Ll; i += 64) str[i] = trans[i];
    __syncthreads();

    // Et[l] = exp(trans[l][ml]) as 48 named scalars — static accesses only.
#define MK_E(l) float E##l = fexp2(str[(l) * Ll + ml] * LOG2E_F);
    MK_E(0)  MK_E(1)  MK_E(2)  MK_E(3)  MK_E(4)  MK_E(5)  MK_E(6)  MK_E(7)
    MK_E(8)  MK_E(9)  MK_E(10) MK_E(11) MK_E(12) MK_E(13) MK_E(14) MK_E(15)
    MK_E(16) MK_E(17) MK_E(18) MK_E(19) MK_E(20) MK_E(21) MK_E(22) MK_E(23)
    MK_E(24) MK_E(25) MK_E(26) MK_E(27) MK_E(28) MK_E(29) MK_E(30) MK_E(31)
    MK_E(32) MK_E(33) MK_E(34) MK_E(35) MK_E(36) MK_E(37) MK_E(38) MK_E(39)
    MK_E(40) MK_E(41) MK_E(42) MK_E(43) MK_E(44) MK_E(45) MK_E(46) MK_E(47)
#undef MK_E

    const float* __restrict__ yprow = y_pred + (size_t)b * Tt * Ll;
    const float* __restrict__ ytrow = y_true + (size_t)b * Tt * Ll;

    // t = 0 init
    float raw0 = yprow[ml];
    float e = fexp2(raw0 * LOG2E_F);    // e_0[m] = 2^(alpha0[m]*log2e), S=0
    float S = 0.f;                      // accumulated log2 normalizers
    float ts = 0.f;

    unsigned long long m0 = __ballot(act && (ytrow[ml] > 0.5f));
    int labPrev = __ffsll(m0) - 1;
    float ps = rl_f(raw0, labPrev);     // point score, t=0 term

    // One scan step as a macro — no lambda, no capture frame, no address-taken
    // locals. ebuf[0] (normalizer) is read FIRST so log/exp overlap the fmacs.
#define ACC4(j)                                                          \
        { float4 bc = *(const float4*)&ebuf[4*(j)];                      \
          a0 = fmaf(bc.x, E##j##_0, a0); a1 = fmaf(bc.y, E##j##_1, a1);  \
          a2 = fmaf(bc.z, E##j##_2, a2); a3 = fmaf(bc.w, E##j##_3, a3); }
#define E_AL(j,a,b_,c_,d_) /* alias group j to scalar names */
    // group aliases: E<j>_0..3 == E(4j)..E(4j+3)
#define EG(j)  E##j
#define STEP(raw, ytv)                                                   \
    do {                                                                 \
        ebuf[lane] = e;                                                  \
        float e0 = ebuf[0];                     /* uniform ds_read    */ \
        float c  = flog2(e0);                                            \
        S += c;                                                          \
        float w = fexp2(fmaf((raw), LOG2E_F, -c));                       \
        unsigned long long bm = __ballot(act && ((ytv) > 0.5f));         \
        int lab = __ffsll(bm) - 1;                                       \
        ps += rl_f((raw), lab);                                          \
        ts += str[labPrev * Ll + lab];                                   \
        labPrev = lab;                                                   \
        float a0 = 0.f, a1 = 0.f, a2 = 0.f, a3 = 0.f;                    \
        { float4 bc = *(const float4*)&ebuf[0];                          \
          a0 = fmaf(bc.x, E0,  a0); a1 = fmaf(bc.y, E1,  a1);            \
          a2 = fmaf(bc.z, E2,  a2); a3 = fmaf(bc.w, E3,  a3); }          \
        { float4 bc = *(const float4*)&ebuf[4];                          \
          a0 = fmaf(bc.x, E4,  a0); a1 = fmaf(bc.y, E5,  a1);            \
          a2 = fmaf(bc.z, E6,  a2); a3 = fmaf(bc.w, E7,  a3); }          \
        { float4 bc = *(const float4*)&ebuf[8];                          \
          a0 = fmaf(bc.x, E8,  a0); a1 = fmaf(bc.y, E9,  a1);            \
          a2 = fmaf(bc.z, E10, a2); a3 = fmaf(bc.w, E11, a3); }          \
        { float4 bc = *(const float4*)&ebuf[12];                         \
          a0 = fmaf(bc.x, E12, a0); a1 = fmaf(bc.y, E13, a1);            \
          a2 = fmaf(bc.z, E14, a2); a3 = fmaf(bc.w, E15, a3); }          \
        { float4 bc = *(const float4*)&ebuf[16];                         \
          a0 = fmaf(bc.x, E16, a0); a1 = fmaf(bc.y, E17, a1);            \
          a2 = fmaf(bc.z, E18, a2); a3 = fmaf(bc.w, E19, a3); }          \
        { float4 bc = *(const float4*)&ebuf[20];                         \
          a0 = fmaf(bc.x, E20, a0); a1 = fmaf(bc.y, E21, a1);            \
          a2 = fmaf(bc.z, E22, a2); a3 = fmaf(bc.w, E23, a3); }          \
        { float4 bc = *(const float4*)&ebuf[24];                         \
          a0 = fmaf(bc.x, E24, a0); a1 = fmaf(bc.y, E25, a1);            \
          a2 = fmaf(bc.z, E26, a2); a3 = fmaf(bc.w, E27, a3); }          \
        { float4 bc = *(const float4*)&ebuf[28];                         \
          a0 = fmaf(bc.x, E28, a0); a1 = fmaf(bc.y, E29, a1);            \
          a2 = fmaf(bc.z, E30, a2); a3 = fmaf(bc.w, E31, a3); }          \
        { float4 bc = *(const float4*)&ebuf[32];                         \
          a0 = fmaf(bc.x, E32, a0); a1 = fmaf(bc.y, E33, a1);            \
          a2 = fmaf(bc.z, E34, a2); a3 = fmaf(bc.w, E35, a3); }          \
        { float4 bc = *(const float4*)&ebuf[36];                         \
          a0 = fmaf(bc.x, E36, a0); a1 = fmaf(bc.y, E37, a1);            \
          a2 = fmaf(bc.z, E38, a2); a3 = fmaf(bc.w, E39, a3); }          \
        { float4 bc = *(const float4*)&ebuf[40];                         \
          a0 = fmaf(bc.x, E40, a0); a1 = fmaf(bc.y, E41, a1);            \
          a2 = fmaf(bc.z, E42, a2); a3 = fmaf(bc.w, E43, a3); }          \
        { float4 bc = *(const float4*)&ebuf[44];                         \
          a0 = fmaf(bc.x, E44, a0); a1 = fmaf(bc.y, E45, a1);            \
          a2 = fmaf(bc.z, E46, a2); a3 = fmaf(bc.w, E47, a3); }          \
        e = ((a0 + a1) + (a2 + a3)) * w;                                 \
    } while (0)

    // prefetch pipeline: pfP/pfT hold rows t0..t0+PF-1
    float pfP[PF], pfT[PF];
    #pragma unroll
    for (int j = 0; j < PF; ++j) {
        pfP[j] = yprow[(1 + j) * Ll + ml];
        pfT[j] = ytrow[(1 + j) * Ll + ml];
    }

    // main: steps t = 1..1020 in chunks of PF
    for (int t0 = 1; t0 <= Tt - PF - 3; t0 += PF) {
        #pragma unroll
        for (int j = 0; j < PF; ++j) {
            float raw = pfP[j];
            float ytv = pfT[j];
            int tn = t0 + j + PF;
            tn = tn < Tt ? tn : (Tt - 1);           // clamp (harmless reload)
            pfP[j] = yprow[tn * Ll + ml];
            pfT[j] = ytrow[tn * Ll + ml];
            STEP(raw, ytv);
        }
    }
    // tail: t = 1021, 1022, 1023
    STEP(pfP[0], pfT[0]);
    STEP(pfP[1], pfT[1]);
    STEP(pfP[2], pfT[2]);
#undef STEP
#undef ACC4

    // epilogue: log_norm = ln2 * (S + log2(sum_m e[m]))
    float es = act ? e : 0.f;
    #pragma unroll
    for (int off = 32; off >= 1; off >>= 1) es += __shfl_xor(es, off);

    if (lane == 0) {
        float log_norm = LN2_F * (S + flog2(es));
        out[b] = log_norm - ps - ts;
    }
}

extern "C" void kernel_launch(void* const* d_in, const int* in_sizes, int n_in,
                              void* d_out, int out_size, void* d_ws, size_t ws_size,
                              hipStream_t stream) {
    const float* y_true = (const float*)d_in[0];
    const float* y_pred = (const float*)d_in[1];
    const float* trans  = (const float*)d_in[2];
    float* out = (float*)d_out;

    crf_fwd_kernel<<<Bb, 64, 0, stream>>>(y_true, y_pred, trans, out);
}